// Round 13
// baseline (723.632 us; speedup 1.0000x reference)
//
#include <hip/hip_runtime.h>

#define BB 1024
#define TT 512
#define CC 41
#define BPS 48   // bp row stride (41 used + pad); lane<48 single-branch stores

__device__ __forceinline__ float rlanef(float xv, int l) {
    return __int_as_float(__builtin_amdgcn_readlane(__float_as_int(xv), l));
}

__global__ __launch_bounds__(64, 1) void crf_viterbi_kernel(
    const float* __restrict__ x,
    const float* __restrict__ start_t,
    const float* __restrict__ end_t,
    const float* __restrict__ trans,
    int* __restrict__ out)   // harness reads out_size int32 elements
{
    // Two independent batch streams per wave.
    __shared__ unsigned char bp0_lds[TT * BPS + 64];   // rows 0..510 + read-pad
    __shared__ unsigned char bp1_lds[TT * BPS + 64];
    __shared__ int tags0_lds[TT];
    __shared__ int tags1_lds[TT];

    const int lane = threadIdx.x;
    const int c = (lane < CC) ? lane : (CC - 1);   // clamp for safe loads

    // trans column c (shared by both streams)
    float trans_reg[CC];
    #pragma unroll
    for (int p = 0; p < CC; ++p) trans_reg[p] = trans[p * CC + c];

    const int b0 = blockIdx.x * 2;
    const int b1 = b0 + 1;
    const float* xb0 = x + (size_t)b0 * TT * CC;
    const float* xb1 = x + (size_t)b1 * TT * CC;

    // t = 0: score0 = start_transitions + x[:,0]   (exact ref op order)
    float sc0 = start_t[c] + xb0[c];
    float sc1 = start_t[c] + xb1[c];

    // 3-deep emit prefetch per stream
    float e0a = xb0[1 * CC + c], e0b = xb0[2 * CC + c], e0c = xb0[3 * CC + c];
    float e1a = xb1[1 * CC + c], e1b = xb1[2 * CC + c], e1c = xb1[3 * CC + c];

    for (int t = 1; t < TT; ++t) {
        const int tf = (t + 3 < TT) ? (t + 3) : (TT - 1);
        const float f0 = xb0[(size_t)tf * CC + c];
        const float f1 = xb1[(size_t)tf * CC + c];

        // Candidates, both streams: exact ref op order (score + trans) + emit.
        float v0[CC], v1[CC];
        int  ix0[CC], ix1[CC];
        #pragma unroll
        for (int p = 0; p < CC; ++p) {
            const float s0p = rlanef(sc0, p);
            const float s1p = rlanef(sc1, p);
            v0[p] = (s0p + trans_reg[p]) + e0a;  ix0[p] = p;
            v1[p] = (s1p + trans_reg[p]) + e1a;  ix1[p] = p;
        }

        // Segment-tree argmax (depth 6), contiguous blocks: keep-left on
        // strict > == jnp.argmax first-occurrence. Two independent trees
        // interleaved -> fills dependency bubbles.
#define CSTEP(V, IX, i, j) do { \
            if (V[(j)] > V[(i)]) { V[(i)] = V[(j)]; IX[(i)] = IX[(j)]; } \
        } while (0)
        #pragma unroll
        for (int i = 0; i < 20; ++i) { CSTEP(v0, ix0, 2*i, 2*i+1); CSTEP(v1, ix1, 2*i, 2*i+1); }
        #pragma unroll
        for (int i = 0; i < 10; ++i) { CSTEP(v0, ix0, 4*i, 4*i+2); CSTEP(v1, ix1, 4*i, 4*i+2); }
        #pragma unroll
        for (int i = 0; i < 5;  ++i) { CSTEP(v0, ix0, 8*i, 8*i+4); CSTEP(v1, ix1, 8*i, 8*i+4); }
        CSTEP(v0, ix0, 0, 8);   CSTEP(v1, ix1, 0, 8);
        CSTEP(v0, ix0, 16, 24); CSTEP(v1, ix1, 16, 24);
        CSTEP(v0, ix0, 0, 16);  CSTEP(v1, ix1, 0, 16);
        CSTEP(v0, ix0, 32, 40); CSTEP(v1, ix1, 32, 40);
        CSTEP(v0, ix0, 0, 32);  CSTEP(v1, ix1, 0, 32);
#undef CSTEP

        sc0 = v0[0];
        sc1 = v1[0];
        if (lane < BPS) {   // one branch, two stores; pad cols never read
            bp0_lds[(t - 1) * BPS + lane] = (unsigned char)ix0[0];
            bp1_lds[(t - 1) * BPS + lane] = (unsigned char)ix1[0];
        }

        e0a = e0b; e0b = e0c; e0c = f0;
        e1a = e1b; e1b = e1c; e1c = f1;
    }

    // final = score + end_transitions   (exact ref op order)
    const float fin0 = sc0 + end_t[c];
    const float fin1 = sc1 + end_t[c];

    // Final argmax (first occurrence), two interleaved readlane scans.
    float bv0 = rlanef(fin0, 0); int tag0 = 0;
    float bv1 = rlanef(fin1, 0); int tag1 = 0;
    #pragma unroll
    for (int i = 1; i < CC; ++i) {
        const float q0 = rlanef(fin0, i);
        const float q1 = rlanef(fin1, i);
        if (q0 > bv0) { bv0 = q0; tag0 = i; }
        if (q1 > bv1) { bv1 = q1; tag1 = i; }
    }

    __syncthreads();   // drain bp writes (single wave: cheap)

    // Pipelined backtrack (proven R10): batch-load 16 rows per stream, then
    // resolve via readlane chains (uniform index); two chains interleave.
    if (lane == 0) { tags0_lds[TT - 1] = tag0; tags1_lds[TT - 1] = tag1; }
    for (int g = 31; g >= 0; --g) {
        const int base = g * 16;
        unsigned int r0[16], r1[16];
        #pragma unroll
        for (int j = 0; j < 16; ++j) {
            r0[j] = (unsigned int)bp0_lds[(base + j) * BPS + lane];
            r1[j] = (unsigned int)bp1_lds[(base + j) * BPS + lane];
        }
        #pragma unroll
        for (int j = 15; j >= 0; --j) {
            const int r = base + j;          // row r maps tag@r+1 -> tag@r
            if (r < TT - 1) {
                tag0 = (int)__builtin_amdgcn_readlane((int)r0[j], tag0);
                tag1 = (int)__builtin_amdgcn_readlane((int)r1[j], tag1);
                if (lane == 0) { tags0_lds[r] = tag0; tags1_lds[r] = tag1; }
            }
        }
    }
    __syncthreads();

    // coalesced output writes
    int* ob0 = out + (size_t)b0 * TT;
    int* ob1 = out + (size_t)b1 * TT;
    #pragma unroll
    for (int i = 0; i < TT / 64; ++i) {
        ob0[lane + 64 * i] = tags0_lds[lane + 64 * i];
        ob1[lane + 64 * i] = tags1_lds[lane + 64 * i];
    }
}

extern "C" void kernel_launch(void* const* d_in, const int* in_sizes, int n_in,
                              void* d_out, int out_size, void* d_ws, size_t ws_size,
                              hipStream_t stream) {
    (void)in_sizes; (void)n_in; (void)d_ws; (void)ws_size; (void)out_size;
    const float* x       = (const float*)d_in[0];
    const float* start_t = (const float*)d_in[1];
    const float* end_t   = (const float*)d_in[2];
    const float* trans   = (const float*)d_in[3];
    int* out = (int*)d_out;

    crf_viterbi_kernel<<<dim3(BB / 2), dim3(64), 0, stream>>>(x, start_t, end_t, trans, out);
}